// Round 2
// baseline (221.857 us; speedup 1.0000x reference)
//
#include <hip/hip_runtime.h>
#include <stdint.h>

typedef __bf16 bf16x8 __attribute__((ext_vector_type(8)));
typedef float  f32x4  __attribute__((ext_vector_type(4)));

#define NB   32
#define CI   128
#define HH   56
#define WW   56
#define CO   256
#define HP   58          // 56 + 2 halo
#define HW   (HH*WW)     // 3136
#define MTOT (NB*HW)     // 100352
#define KTOT 1152        // 9*128, k = (r*3+s)*128 + c

#define XT_ELEMS ((size_t)NB*HP*HP*CI)   // 13,778,944
#define XT_BYTES (XT_ELEMS*2)            // 27,557,888 (16B-aligned)

// ---------- zero only the halo ring of padded x_t ----------
__global__ void halo_zero(__bf16* __restrict__ xt) {
  int id = blockIdx.x * 256 + threadIdx.x;
  if (id >= NB * 228 * 16) return;
  int chunk = id & 15;
  int p = (id >> 4) % 228;
  int n = id / (228 * 16);
  int h, w;
  if (p < 58)       { h = 0;           w = p; }
  else if (p < 116) { h = 57;          w = p - 58; }
  else if (p < 172) { h = p - 116 + 1; w = 0; }
  else              { h = p - 172 + 1; w = 57; }
  int4* dst = (int4*)(xt + ((size_t)(n * HP + h) * HP + w) * CI) + chunk;
  *dst = make_int4(0, 0, 0, 0);
}

// ---------- x: NCHW f32 -> padded NHWC bf16 (LDS transpose per (n,h)) ----------
__global__ void xpose_kernel(const float* __restrict__ x, __bf16* __restrict__ xt) {
  int nh = blockIdx.x;
  int n = nh / HH, h = nh % HH;
  __shared__ float tile[CI][57];
  const float* src = x + (size_t)n * CI * HW + (size_t)h * WW;
  int t = threadIdx.x;
  for (int idx = t; idx < CI * 14; idx += 256) {
    int c = idx / 14, w4 = idx - c * 14;
    float4 v = *(const float4*)(src + (size_t)c * HW + w4 * 4);
    tile[c][w4 * 4 + 0] = v.x;
    tile[c][w4 * 4 + 1] = v.y;
    tile[c][w4 * 4 + 2] = v.z;
    tile[c][w4 * 4 + 3] = v.w;
  }
  __syncthreads();
  __bf16* dst = xt + ((size_t)(n * HP + h + 1) * HP + 1) * CI;
  for (int idx = t; idx < WW * 16; idx += 256) {
    int w = idx >> 4, c8 = (idx & 15) * 8;
    bf16x8 v;
    for (int k = 0; k < 8; ++k) v[k] = (__bf16)tile[c8 + k][w];
    *(bf16x8*)(dst + (size_t)w * CI + c8) = v;
  }
}

// ---------- weight: OIHW f32 -> [CO][KTOT] bf16, k=(r*3+s)*128+c ----------
__global__ void wxform_kernel(const float* __restrict__ wg, __bf16* __restrict__ wt) {
  int id = blockIdx.x * 256 + threadIdx.x;   // CO*KTOT = 294912 total
  int o = id / KTOT;
  int k = id - o * KTOT;
  int rs = k >> 7, c = k & 127;
  wt[id] = (__bf16)wg[(size_t)o * KTOT + c * 9 + rs];
}

// ---------- implicit-GEMM conv: 3-buffer pipeline + 8-phase-style schedule ----------
// Frame identical to round 1 (verified): BM=128, BN=256 (all out-ch per block ->
// A fetched once, B L2-resident), BK=64, 128-B LDS rows XOR-swizzled via
// pre-swizzled GLOBAL source (linear gload_lds dest), 3 buffers, vmcnt(6)
// tile-boundary wait (never 0 in main loop).
// NEW (T3+T4 proper): each K-tile = 2 phases of 16 MFMA, each phase
// {8 ds_read ∥ stage issues -> s_barrier -> lgkmcnt(0)+sched_barrier ->
//  setprio(1) 16 MFMA setprio(0) -> s_barrier}. This is the m201/m218 fine
// interleave; coarse clusters + counted vmcnt alone measured at the 2-phase
// ceiling (677 TF ≈ m230's 682).
#define BM 128
#define BN 256
#define NKT 18   // KTOT/64

#define STAGE_A2(BS, OFF) \
  { _Pragma("unroll") for (int i_ = 0; i_ < 2; ++i_) \
      __builtin_amdgcn_global_load_lds( \
        (const __attribute__((address_space(1))) void*)(xtc + baseA[i_] + (OFF)), \
        (__attribute__((address_space(3))) void*)(lds + (BS)*16384 + i_*8192 + ldst), 16, 0, 0); }

#define STAGE_B01(BS, OFF) \
  { _Pragma("unroll") for (int i_ = 0; i_ < 2; ++i_) \
      __builtin_amdgcn_global_load_lds( \
        (const __attribute__((address_space(1))) void*)(wtc + baseB[i_] + (OFF)), \
        (__attribute__((address_space(3))) void*)(lds + 49152 + (BS)*32768 + i_*8192 + ldst), 16, 0, 0); }

#define STAGE_B23(BS, OFF) \
  { _Pragma("unroll") for (int i_ = 2; i_ < 4; ++i_) \
      __builtin_amdgcn_global_load_lds( \
        (const __attribute__((address_space(1))) void*)(wtc + baseB[i_] + (OFF)), \
        (__attribute__((address_space(3))) void*)(lds + 49152 + (BS)*32768 + i_*8192 + ldst), 16, 0, 0); }

// One K-tile, two 16-MFMA phases. Buf safety: stages for kt+2 write buf
// (kt-1)%3; all reads of that buf drained (per-wave lgkmcnt before tile kt-1's
// final barrier) before any wave issues these stages.
#define KBODY(KT, BC, BS, DOSTAGE, DOBAR, VMCLIT) do { \
  int kt2_ = (KT) + 2; \
  int rs2_ = kt2_ >> 1; int r2_ = (rs2_*11)>>5; int s2_ = rs2_ - 3*r2_; \
  uint32_t offA2_ = (uint32_t)((r2_*HP + s2_) * 256 + (kt2_ & 1) * 128); \
  uint32_t offB2_ = (uint32_t)(kt2_ * 128); \
  const char* Ab_ = lds + (BC)*16384; \
  const char* Bb_ = lds + 49152 + (BC)*32768; \
  /* ---------------- phase 0: k-slice 0 ---------------- */ \
  { \
    bf16x8 av_[4], bv_[4]; \
    _Pragma("unroll") for (int a_ = 0; a_ < 4; ++a_) \
      av_[a_] = *(const bf16x8*)(Ab_ + rowA + a_*2048 + slot0); \
    _Pragma("unroll") for (int b_ = 0; b_ < 4; ++b_) \
      bv_[b_] = *(const bf16x8*)(Bb_ + rowB + b_*2048 + slot0); \
    if (DOSTAGE) { STAGE_A2(BS, offA2_); STAGE_B01(BS, offB2_); } \
    __builtin_amdgcn_s_barrier(); \
    asm volatile("s_waitcnt lgkmcnt(0)" ::: "memory"); \
    __builtin_amdgcn_sched_barrier(0); \
    __builtin_amdgcn_s_setprio(1); \
    _Pragma("unroll") for (int a_ = 0; a_ < 4; ++a_) \
      _Pragma("unroll") for (int b_ = 0; b_ < 4; ++b_) \
        acc[a_][b_] = __builtin_amdgcn_mfma_f32_16x16x32_bf16(av_[a_], bv_[b_], acc[a_][b_], 0, 0, 0); \
    __builtin_amdgcn_s_setprio(0); \
    __builtin_amdgcn_s_barrier(); \
  } \
  /* ---------------- phase 1: k-slice 1 ---------------- */ \
  { \
    bf16x8 av_[4], bv_[4]; \
    _Pragma("unroll") for (int a_ = 0; a_ < 4; ++a_) \
      av_[a_] = *(const bf16x8*)(Ab_ + rowA + a_*2048 + slot1); \
    _Pragma("unroll") for (int b_ = 0; b_ < 4; ++b_) \
      bv_[b_] = *(const bf16x8*)(Bb_ + rowB + b_*2048 + slot1); \
    if (DOSTAGE) { STAGE_B23(BS, offB2_); } \
    __builtin_amdgcn_s_barrier(); \
    asm volatile("s_waitcnt lgkmcnt(0)" ::: "memory"); \
    __builtin_amdgcn_sched_barrier(0); \
    __builtin_amdgcn_s_setprio(1); \
    _Pragma("unroll") for (int a_ = 0; a_ < 4; ++a_) \
      _Pragma("unroll") for (int b_ = 0; b_ < 4; ++b_) \
        acc[a_][b_] = __builtin_amdgcn_mfma_f32_16x16x32_bf16(av_[a_], bv_[b_], acc[a_][b_], 0, 0, 0); \
    __builtin_amdgcn_s_setprio(0); \
    if (DOBAR) { \
      asm volatile("s_waitcnt vmcnt(" VMCLIT ")" ::: "memory"); \
      __builtin_amdgcn_sched_barrier(0); \
      __builtin_amdgcn_s_barrier(); \
      __builtin_amdgcn_sched_barrier(0); \
    } \
  } \
} while (0)

__global__ __launch_bounds__(512, 2) void conv_gemm(
    const __bf16* __restrict__ xt, const __bf16* __restrict__ wt,
    const float* __restrict__ bias, float* __restrict__ out) {
  // LDS: A bufs 3x16384 @0 ; B bufs 3x32768 @49152 ; total 147456 B (<=160K)
  __shared__ char lds[147456];
  int t = threadIdx.x;
  int mb = blockIdx.x;
  const char* xtc = (const char*)xt;
  const char* wtc = (const char*)wt;

  // ---- staging: linear LDS dest (t*16), PRE-SWIZZLED global source ----
  int arow = t >> 3;                                        // 0..63
  int kbsrc = ((t & 7) * 16) ^ ((arow & 7) << 4);           // swizzled slot in [0,128)
  int ldst = t * 16;
  uint32_t baseA[2];
#pragma unroll
  for (int i = 0; i < 2; ++i) {
    unsigned m = mb * BM + i * 64 + arow;
    unsigned nimg = m / HW;
    unsigned hw = m - nimg * HW;
    unsigned h = hw / WW;
    unsigned w = hw - h * WW;
    baseA[i] = ((nimg * HP + h) * HP + w) * (CI * 2) + kbsrc;
  }
  uint32_t baseB[4];
#pragma unroll
  for (int i = 0; i < 4; ++i)
    baseB[i] = (i * 64 + arow) * (KTOT * 2) + kbsrc;

  // ---- per-wave geometry: 8 waves = 2M x 4N, each 64x64 (4x4 fragments) ----
  int wid = t >> 6, lane = t & 63;
  int wm = (wid >> 2) * 64;        // 0,64
  int wn = (wid & 3) * 64;         // 0,64,128,192
  int lr = lane & 15, hi = lane >> 4;
  int swz = (lr & 7) << 4;
  int slot0 = (hi * 16) ^ swz;         // kk=0 slice, swizzled
  int slot1 = (64 + hi * 16) ^ swz;    // kk=1 slice
  int rowA = (wm + lr) * 128;          // + a*2048
  int rowB = (wn + lr) * 128;          // + b*2048

  f32x4 acc[4][4];
#pragma unroll
  for (int i = 0; i < 4; ++i)
#pragma unroll
    for (int j = 0; j < 4; ++j) acc[i][j] = (f32x4){0.f, 0.f, 0.f, 0.f};

  // ---- prologue: stage kt=0 -> buf0, kt=1 -> buf1 (12 issues) ----
  STAGE_A2(0, 0u);   STAGE_B01(0, 0u);   STAGE_B23(0, 0u);
  STAGE_A2(1, 128u); STAGE_B01(1, 128u); STAGE_B23(1, 128u);
  asm volatile("s_waitcnt vmcnt(6)" ::: "memory");   // kt0's 6 confirmed
  __builtin_amdgcn_sched_barrier(0);
  __builtin_amdgcn_s_barrier();
  __builtin_amdgcn_sched_barrier(0);

  // ---- main loop: 5 x 3 bodies (kt 0..14), buffers cycle 0,1,2 ----
  for (int kt = 0; kt < 15; kt += 3) {
    KBODY(kt + 0, 0, 2, 1, 1, "6");
    KBODY(kt + 1, 1, 0, 1, 1, "6");
    KBODY(kt + 2, 2, 1, 1, 1, "6");
  }
  // ---- tail: kt=15 stages kt17; kt=16 drains; kt=17 computes only ----
  KBODY(15, 0, 2, 1, 1, "6");
  KBODY(16, 1, 0, 0, 1, "0");
  KBODY(17, 2, 1, 0, 0, "0");

  // ---- epilogue: C/D layout col(=o)=lane&15, row(=m)=(lane>>4)*4+reg ----
#pragma unroll
  for (int j = 0; j < 4; ++j) {
    int o = wn + j * 16 + lr;
    float bv = bias[o];
#pragma unroll
    for (int i = 0; i < 4; ++i) {
      unsigned m0 = mb * BM + wm + i * 16 + hi * 4;
      unsigned nimg = m0 / HW;
      unsigned hw = m0 - nimg * HW;
      f32x4 v = acc[i][j];
      v[0] += bv; v[1] += bv; v[2] += bv; v[3] += bv;
      *(f32x4*)(out + ((size_t)nimg * CO + o) * HW + hw) = v;
    }
  }
}

extern "C" void kernel_launch(void* const* d_in, const int* in_sizes, int n_in,
                              void* d_out, int out_size, void* d_ws, size_t ws_size,
                              hipStream_t stream) {
  const float* x    = (const float*)d_in[0];
  const float* wg   = (const float*)d_in[1];
  const float* bias = (const float*)d_in[2];
  float* out = (float*)d_out;

  __bf16* xt = (__bf16*)d_ws;
  __bf16* wt = (__bf16*)((char*)d_ws + XT_BYTES);

  halo_zero<<<(NB * 228 * 16 + 255) / 256, 256, 0, stream>>>(xt);
  xpose_kernel<<<NB * HH, 256, 0, stream>>>(x, xt);
  wxform_kernel<<<(CO * KTOT) / 256, 256, 0, stream>>>(wg, wt);
  conv_gemm<<<MTOT / BM, 512, 0, stream>>>(xt, wt, bias, out);
}

// Round 4
// 219.513 us; speedup vs baseline: 1.0107x; 1.0107x over previous
//
#include <hip/hip_runtime.h>
#include <stdint.h>

typedef __bf16 bf16x8 __attribute__((ext_vector_type(8)));
typedef float  f32x4  __attribute__((ext_vector_type(4)));

#define NB   32
#define CI   128
#define HH   56
#define WW   56
#define CO   256
#define HP   58          // 56 + 2 halo
#define HW   (HH*WW)     // 3136
#define MTOT (NB*HW)     // 100352
#define KTOT 1152        // 9*128, k = (r*3+s)*128 + c

#define XT_ELEMS ((size_t)NB*HP*HP*CI)   // 13,778,944
#define XT_BYTES (XT_ELEMS*2)            // 27,557,888 (16B-aligned)

// ---------- zero only the halo ring of padded x_t ----------
__global__ void halo_zero(__bf16* __restrict__ xt) {
  int id = blockIdx.x * 256 + threadIdx.x;
  if (id >= NB * 228 * 16) return;
  int chunk = id & 15;
  int p = (id >> 4) % 228;
  int n = id / (228 * 16);
  int h, w;
  if (p < 58)       { h = 0;           w = p; }
  else if (p < 116) { h = 57;          w = p - 58; }
  else if (p < 172) { h = p - 116 + 1; w = 0; }
  else              { h = p - 172 + 1; w = 57; }
  int4* dst = (int4*)(xt + ((size_t)(n * HP + h) * HP + w) * CI) + chunk;
  *dst = make_int4(0, 0, 0, 0);
}

// ---------- x: NCHW f32 -> padded NHWC bf16 (LDS transpose per (n,h)) ----------
__global__ void xpose_kernel(const float* __restrict__ x, __bf16* __restrict__ xt) {
  int nh = blockIdx.x;
  int n = nh / HH, h = nh % HH;
  __shared__ float tile[CI][57];
  const float* src = x + (size_t)n * CI * HW + (size_t)h * WW;
  int t = threadIdx.x;
  for (int idx = t; idx < CI * 14; idx += 256) {
    int c = idx / 14, w4 = idx - c * 14;
    float4 v = *(const float4*)(src + (size_t)c * HW + w4 * 4);
    tile[c][w4 * 4 + 0] = v.x;
    tile[c][w4 * 4 + 1] = v.y;
    tile[c][w4 * 4 + 2] = v.z;
    tile[c][w4 * 4 + 3] = v.w;
  }
  __syncthreads();
  __bf16* dst = xt + ((size_t)(n * HP + h + 1) * HP + 1) * CI;
  for (int idx = t; idx < WW * 16; idx += 256) {
    int w = idx >> 4, c8 = (idx & 15) * 8;
    bf16x8 v;
    for (int k = 0; k < 8; ++k) v[k] = (__bf16)tile[c8 + k][w];
    *(bf16x8*)(dst + (size_t)w * CI + c8) = v;
  }
}

// ---------- weight: OIHW f32 -> [CO][KTOT] bf16, k=(r*3+s)*128+c ----------
__global__ void wxform_kernel(const float* __restrict__ wg, __bf16* __restrict__ wt) {
  int id = blockIdx.x * 256 + threadIdx.x;   // CO*KTOT = 294912 total
  int o = id / KTOT;
  int k = id - o * KTOT;
  int rs = k >> 7, c = k & 127;
  wt[id] = (__bf16)wg[(size_t)o * KTOT + c * 9 + rs];
}

// ---------- implicit-GEMM conv: m201 geometry (256x256, 128x64 wave tiles) ----------
// Phase read-row map (the round-3 bug): ph0/ph1 read A rows {0..63, 128..191}
// (= stage issues i 0,2), ph2/ph3 read rows {64..127, 192..255} (= issues 1,3).
// Staging is therefore split by ISSUE PARITY:
//   ph0 of kt -> buf Q (all free since kt-1's final barrier): kt+1's A-odd + B (6)
//   ph2 of kt -> buf P: kt+2's A-even (2) -- exactly the rows drained at ph1's
//   end barrier, disjoint from ph2/ph3 reads.  End-of-tile s_waitcnt vmcnt(2)
//   (counted, never 0 in main loop): leaves only the 2 ph2 issues outstanding,
//   so tile kt+1's data (6 from ph0 of kt, 2 from ph2 of kt-1) is complete.
// Swizzle pair (pre-swizzled global src + swizzled ds_read) verified r1-r2
// (SQ_LDS_BANK_CONFLICT = 0).
#define BM 256
#define BN 256
#define NKT 18   // KTOT/64

// Each issue: 512 thr x 16 B = 8 KB = 64 rows x 128 B.
// LDS map: buf b at b*65536; A [0,32768) rows 0..255; B [32768,65536) rows 0..255.
#define STAGE_A_EVEN(BUF, OFF) /* rows 0..63 & 128..191 */ \
  { _Pragma("unroll") for (int i_ = 0; i_ < 4; i_ += 2) \
      __builtin_amdgcn_global_load_lds( \
        (const __attribute__((address_space(1))) void*)(xtc + baseA[i_] + (OFF)), \
        (__attribute__((address_space(3))) void*)(lds + (BUF)*65536 + i_*8192 + ldst), 16, 0, 0); }

#define STAGE_A_ODD(BUF, OFF) /* rows 64..127 & 192..255 */ \
  { _Pragma("unroll") for (int i_ = 1; i_ < 4; i_ += 2) \
      __builtin_amdgcn_global_load_lds( \
        (const __attribute__((address_space(1))) void*)(xtc + baseA[i_] + (OFF)), \
        (__attribute__((address_space(3))) void*)(lds + (BUF)*65536 + i_*8192 + ldst), 16, 0, 0); }

#define STAGE_B4(BUF, OFF) \
  { _Pragma("unroll") for (int i_ = 0; i_ < 4; ++i_) \
      __builtin_amdgcn_global_load_lds( \
        (const __attribute__((address_space(1))) void*)(wtc + baseB[i_] + (OFF)), \
        (__attribute__((address_space(3))) void*)(lds + (BUF)*65536 + 32768 + i_*8192 + ldst), 16, 0, 0); }

#define PHASE_SYNC() \
  __builtin_amdgcn_s_barrier(); \
  asm volatile("s_waitcnt lgkmcnt(0)" ::: "memory"); \
  __builtin_amdgcn_sched_barrier(0);

// One K-tile = 4 phases x 16 MFMA. P = KT&1 (compile-time).
// DOSTQ: stage tile KT+1's A-odd + B into buf Q at ph0.
// DOSTP: stage tile KT+2's A-even into buf P at ph2.
#define KBODY(KT, P, DOSTQ, DOSTP, DOBAR, VMCLIT) do { \
  const int Q_ = 1 - (P); \
  int kt1_ = (KT) + 1, kt2_ = (KT) + 2; \
  int rs1_ = kt1_ >> 1; int r1_ = (rs1_*11)>>5; int s1_ = rs1_ - 3*r1_; \
  int rs2_ = kt2_ >> 1; int r2_ = (rs2_*11)>>5; int s2_ = rs2_ - 3*r2_; \
  uint32_t offA1_ = (uint32_t)((r1_*HP + s1_)*256 + (kt1_&1)*128); \
  uint32_t offB1_ = (uint32_t)(kt1_*128); \
  uint32_t offA2_ = (uint32_t)((r2_*HP + s2_)*256 + (kt2_&1)*128); \
  const char* Ab_ = lds + (P)*65536; \
  const char* Bb_ = lds + (P)*65536 + 32768; \
  bf16x8 bv0_[4], bv1_[4], av_[4]; \
  /* ---- ph0: rows {0..63,128..191} slice0 x b0-3 ---- */ \
  _Pragma("unroll") for (int a_ = 0; a_ < 4; ++a_) \
    av_[a_] = *(const bf16x8*)(Ab_ + aoff0 + a_*2048); \
  _Pragma("unroll") for (int b_ = 0; b_ < 4; ++b_) \
    bv0_[b_] = *(const bf16x8*)(Bb_ + boff0 + b_*2048); \
  if (DOSTQ) { STAGE_A_ODD(Q_, offA1_); STAGE_B4(Q_, offB1_); } \
  PHASE_SYNC(); \
  __builtin_amdgcn_s_setprio(1); \
  _Pragma("unroll") for (int a_ = 0; a_ < 4; ++a_) \
    _Pragma("unroll") for (int b_ = 0; b_ < 4; ++b_) \
      acc[a_][b_] = __builtin_amdgcn_mfma_f32_16x16x32_bf16(av_[a_], bv0_[b_], acc[a_][b_], 0, 0, 0); \
  __builtin_amdgcn_s_setprio(0); \
  __builtin_amdgcn_s_barrier(); \
  /* ---- ph1: same rows slice1 ---- */ \
  _Pragma("unroll") for (int a_ = 0; a_ < 4; ++a_) \
    av_[a_] = *(const bf16x8*)(Ab_ + aoff1 + a_*2048); \
  _Pragma("unroll") for (int b_ = 0; b_ < 4; ++b_) \
    bv1_[b_] = *(const bf16x8*)(Bb_ + boff1 + b_*2048); \
  PHASE_SYNC(); \
  __builtin_amdgcn_s_setprio(1); \
  _Pragma("unroll") for (int a_ = 0; a_ < 4; ++a_) \
    _Pragma("unroll") for (int b_ = 0; b_ < 4; ++b_) \
      acc[a_][b_] = __builtin_amdgcn_mfma_f32_16x16x32_bf16(av_[a_], bv1_[b_], acc[a_][b_], 0, 0, 0); \
  __builtin_amdgcn_s_setprio(0); \
  __builtin_amdgcn_s_barrier(); \
  /* ---- ph2: rows {64..127,192..255} slice0 (even-row regions now free) ---- */ \
  _Pragma("unroll") for (int a_ = 0; a_ < 4; ++a_) \
    av_[a_] = *(const bf16x8*)(Ab_ + aoff0 + 8192 + a_*2048); \
  if (DOSTP) { STAGE_A_EVEN(P, offA2_); } \
  PHASE_SYNC(); \
  __builtin_amdgcn_s_setprio(1); \
  _Pragma("unroll") for (int a_ = 0; a_ < 4; ++a_) \
    _Pragma("unroll") for (int b_ = 0; b_ < 4; ++b_) \
      acc[a_+4][b_] = __builtin_amdgcn_mfma_f32_16x16x32_bf16(av_[a_], bv0_[b_], acc[a_+4][b_], 0, 0, 0); \
  __builtin_amdgcn_s_setprio(0); \
  __builtin_amdgcn_s_barrier(); \
  /* ---- ph3: same rows slice1 ---- */ \
  _Pragma("unroll") for (int a_ = 0; a_ < 4; ++a_) \
    av_[a_] = *(const bf16x8*)(Ab_ + aoff1 + 8192 + a_*2048); \
  PHASE_SYNC(); \
  __builtin_amdgcn_s_setprio(1); \
  _Pragma("unroll") for (int a_ = 0; a_ < 4; ++a_) \
    _Pragma("unroll") for (int b_ = 0; b_ < 4; ++b_) \
      acc[a_+4][b_] = __builtin_amdgcn_mfma_f32_16x16x32_bf16(av_[a_], bv1_[b_], acc[a_+4][b_], 0, 0, 0); \
  __builtin_amdgcn_s_setprio(0); \
  if (DOBAR) { \
    asm volatile("s_waitcnt vmcnt(" VMCLIT ")" ::: "memory"); \
    __builtin_amdgcn_sched_barrier(0); \
    __builtin_amdgcn_s_barrier(); \
    __builtin_amdgcn_sched_barrier(0); \
  } \
} while (0)

__global__ __launch_bounds__(512, 2) void conv_gemm(
    const __bf16* __restrict__ xt, const __bf16* __restrict__ wt,
    const float* __restrict__ bias, float* __restrict__ out) {
  // LDS: 2 buffers x (A 32KB + B 32KB) = 131072 B
  __shared__ char lds[131072];
  int t = threadIdx.x;
  int mb = blockIdx.x;
  const char* xtc = (const char*)xt;
  const char* wtc = (const char*)wt;

  // ---- staging: linear LDS dest (t*16), PRE-SWIZZLED global source ----
  int arow = t >> 3;                                        // 0..63
  int kbsrc = ((t & 7) * 16) ^ ((arow & 7) << 4);           // swizzled slot in [0,128)
  int ldst = t * 16;
  uint32_t baseA[4];
#pragma unroll
  for (int i = 0; i < 4; ++i) {
    unsigned m = mb * BM + i * 64 + arow;
    unsigned nimg = m / HW;
    unsigned hw = m - nimg * HW;
    unsigned h = hw / WW;
    unsigned w = hw - h * WW;
    baseA[i] = ((nimg * HP + h) * HP + w) * (CI * 2) + kbsrc;
  }
  uint32_t baseB[4];
#pragma unroll
  for (int i = 0; i < 4; ++i)
    baseB[i] = (i * 64 + arow) * (KTOT * 2) + kbsrc;

  // ---- per-wave geometry: 8 waves = 2M x 4N, wave tile 128x64 (8x4 frags) ----
  int wid = t >> 6, lane = t & 63;
  int wm = (wid >> 2) * 128;       // 0,128
  int wn = (wid & 3) * 64;         // 0,64,128,192
  int lr = lane & 15, hi = lane >> 4;
  int swz = (lr & 7) << 4;
  int slot0 = (hi * 16) ^ swz;         // kk=0 slice, swizzled
  int slot1 = (64 + hi * 16) ^ swz;    // kk=1 slice
  int aoff0 = (wm + lr) * 128 + slot0; // + a*2048 (+8192 for rows+64)
  int aoff1 = (wm + lr) * 128 + slot1;
  int boff0 = (wn + lr) * 128 + slot0; // + b*2048
  int boff1 = (wn + lr) * 128 + slot1;

  f32x4 acc[8][4];
#pragma unroll
  for (int i = 0; i < 8; ++i)
#pragma unroll
    for (int j = 0; j < 4; ++j) acc[i][j] = (f32x4){0.f, 0.f, 0.f, 0.f};

  // ---- prologue: T0 full (8 issues) + T1's A-even (2) ----
  STAGE_A_EVEN(0, 0u); STAGE_A_ODD(0, 0u); STAGE_B4(0, 0u);
  STAGE_A_EVEN(1, 128u);                    // offA(kt=1) = 128
  asm volatile("s_waitcnt vmcnt(2)" ::: "memory");   // T0 complete, T1.A-even in flight
  __builtin_amdgcn_sched_barrier(0);
  __builtin_amdgcn_s_barrier();
  __builtin_amdgcn_sched_barrier(0);

  // ---- main loop: kt 0..15 steady (vmcnt(2)); tails 16,17 ----
  for (int kt = 0; kt < 16; kt += 2) {
    KBODY(kt,     0, 1, 1, 1, "2");
    KBODY(kt + 1, 1, 1, 1, 1, "2");
  }
  KBODY(16, 0, 1, 0, 1, "0");   // stages T17's A-odd+B; full drain
  KBODY(17, 1, 0, 0, 0, "0");   // compute only

  // ---- epilogue: C/D layout col(=o)=lane&15, row(=m)=(lane>>4)*4+reg ----
#pragma unroll
  for (int j = 0; j < 4; ++j) {
    int o = wn + j * 16 + lr;
    float bv = bias[o];
#pragma unroll
    for (int i = 0; i < 8; ++i) {
      unsigned m0 = mb * BM + wm + i * 16 + hi * 4;
      unsigned nimg = m0 / HW;
      unsigned hw = m0 - nimg * HW;
      f32x4 v = acc[i][j];
      v[0] += bv; v[1] += bv; v[2] += bv; v[3] += bv;
      *(f32x4*)(out + ((size_t)nimg * CO + o) * HW + hw) = v;
    }
  }
}

extern "C" void kernel_launch(void* const* d_in, const int* in_sizes, int n_in,
                              void* d_out, int out_size, void* d_ws, size_t ws_size,
                              hipStream_t stream) {
  const float* x    = (const float*)d_in[0];
  const float* wg   = (const float*)d_in[1];
  const float* bias = (const float*)d_in[2];
  float* out = (float*)d_out;

  __bf16* xt = (__bf16*)d_ws;
  __bf16* wt = (__bf16*)((char*)d_ws + XT_BYTES);

  halo_zero<<<(NB * 228 * 16 + 255) / 256, 256, 0, stream>>>(xt);
  xpose_kernel<<<NB * HH, 256, 0, stream>>>(x, xt);
  wxform_kernel<<<(CO * KTOT) / 256, 256, 0, stream>>>(wg, wt);
  conv_gemm<<<MTOT / BM, 512, 0, stream>>>(xt, wt, bias, out);
}